// Round 6
// baseline (260.008 us; speedup 1.0000x reference)
//
#include <hip/hip_runtime.h>

#define NPTS 100000
#define NJ 24
#define PDIM 64
#define LL 32
#define CC 16
#define JOINT_STRIDE (PDIM*LL*LL*CC)   /* 1<<20 floats = 4 MB per joint */
#define J4 (JOINT_STRIDE/4)            /* float4 stride per joint */
#define ID_STRIDE (LL*LL*CC)           /* 16384 floats = 64 KB slice */
#define RB 100                         /* reduce blocks */
#define PPW 4                          /* points per wave */
#define PPB 16                         /* points per block (4 waves) */
#define NBINS 4096                     /* 4 bits/axis Morton cells */

/* ws layout in 4-byte units */
#define WS_PART 0        /* 300 floats */
#define WS_MI   384      /* 6 floats */
#define WS_HIST 1024     /* 4096 ints */
#define WS_OFFS 5120     /* 4096 ints */
#define WS_KEYS 16384    /* 100000 ints */
#define WS_PERM 131072   /* 100000 ints */
#define WS_NEEDED ((size_t)(WS_PERM + NPTS) * 4)

typedef float f32x4 __attribute__((ext_vector_type(4)));

__global__ __launch_bounds__(256) void k_partial(const float* __restrict__ qp,
                                                 float* __restrict__ partial,
                                                 int* __restrict__ hist) {
    __shared__ float sm[3][256];
    int tid = threadIdx.x;
    /* zero histogram (first 16 blocks cover 4096) */
    int g = blockIdx.x * 256 + tid;
    if (g < NBINS) hist[g] = 0;
    float s0 = 0.f, s1 = 0.f, s2 = 0.f;
    for (int n = g; n < NPTS; n += RB * 256) {
        s0 += qp[n * 3 + 0];
        s1 += qp[n * 3 + 1];
        s2 += qp[n * 3 + 2];
    }
    sm[0][tid] = s0; sm[1][tid] = s1; sm[2][tid] = s2;
    __syncthreads();
    for (int s = 128; s > 0; s >>= 1) {
        if (tid < s) {
            sm[0][tid] += sm[0][tid + s];
            sm[1][tid] += sm[1][tid + s];
            sm[2][tid] += sm[2][tid + s];
        }
        __syncthreads();
    }
    if (tid == 0) {
        partial[blockIdx.x * 3 + 0] = sm[0][0];
        partial[blockIdx.x * 3 + 1] = sm[1][0];
        partial[blockIdx.x * 3 + 2] = sm[2][0];
    }
}

__global__ __launch_bounds__(256) void k_final(const float* __restrict__ partial,
                                               const float* __restrict__ scale,
                                               float* __restrict__ mi) {
    __shared__ float sm[3][256];
    int tid = threadIdx.x;
    float s0 = 0.f, s1 = 0.f, s2 = 0.f;
    if (tid < RB) {
        s0 = partial[tid * 3 + 0];
        s1 = partial[tid * 3 + 1];
        s2 = partial[tid * 3 + 2];
    }
    sm[0][tid] = s0; sm[1][tid] = s1; sm[2][tid] = s2;
    __syncthreads();
    for (int s = 128; s > 0; s >>= 1) {
        if (tid < s) {
            sm[0][tid] += sm[0][tid + s];
            sm[1][tid] += sm[1][tid + s];
            sm[2][tid] += sm[2][tid + s];
        }
        __syncthreads();
    }
    if (tid == 0) {
        const float invn = 1.0f / (float)NPTS;
        mi[0] = sm[0][0] * invn;
        mi[1] = sm[1][0] * invn;
        mi[2] = sm[2][0] * invn;
        mi[3] = 1.0f / (scale[0] * 0.5f);
        mi[4] = 1.0f / (scale[1] * 0.5f);
        mi[5] = 1.0f / (scale[2] * 0.5f);
    }
}

__device__ __forceinline__ unsigned spread3_4(unsigned v) {
    /* 4 bits -> bits 0,3,6,9 */
    return (v & 1u) | ((v & 2u) << 2) | ((v & 4u) << 4) | ((v & 8u) << 6);
}

__global__ __launch_bounds__(256) void k_keys(const float* __restrict__ qp,
                                              const float* __restrict__ mi,
                                              int* __restrict__ keys,
                                              int* __restrict__ hist) {
    int p = blockIdx.x * 256 + threadIdx.x;
    if (p >= NPTS) return;
    const float m0 = mi[0], m1 = mi[1], m2 = mi[2];
    const float i0 = mi[3], i1 = mi[4], i2 = mi[5];
    float cx = (qp[p * 3 + 0] - m0) * i0;
    float cy = (qp[p * 3 + 1] - m1) * i1;
    float cz = (qp[p * 3 + 2] - m2) * i2;
    int kx = min(15, max(0, (int)((cx + 1.0f) * 8.0f)));
    int ky = min(15, max(0, (int)((cy + 1.0f) * 8.0f)));
    int kz = min(15, max(0, (int)((cz + 1.0f) * 8.0f)));
    int key = (int)((spread3_4((unsigned)kx) << 2) |
                    (spread3_4((unsigned)ky) << 1) |
                     spread3_4((unsigned)kz));
    keys[p] = key;
    atomicAdd(&hist[key], 1);
}

__global__ __launch_bounds__(256) void k_scan(const int* __restrict__ hist,
                                              int* __restrict__ offs) {
    __shared__ int part[256];
    int t = threadIdx.x;
    int local[16];
    int s = 0;
    int base = t * 16;
#pragma unroll
    for (int i = 0; i < 16; ++i) { local[i] = hist[base + i]; s += local[i]; }
    part[t] = s;
    __syncthreads();
    int mine = s;
    for (int d = 1; d < 256; d <<= 1) {
        int u = (t >= d) ? part[t - d] : 0;
        __syncthreads();
        part[t] += u;
        __syncthreads();
    }
    int run = part[t] - mine;   /* exclusive prefix */
#pragma unroll
    for (int i = 0; i < 16; ++i) { offs[base + i] = run; run += local[i]; }
}

__global__ __launch_bounds__(256) void k_scatter(const int* __restrict__ keys,
                                                 int* __restrict__ offs,
                                                 int* __restrict__ perm) {
    int p = blockIdx.x * 256 + threadIdx.x;
    if (p >= NPTS) return;
    int key = keys[p];
    int pos = atomicAdd(&offs[key], 1);
    perm[pos] = p;
}

/* wave = 4 (spatially sorted) points; lane = (pt, jg, cq).
   SORTED: p = perm[i] so the 4 points share Morton cell -> corner lines
   coalesce across lanes. Gathers dwordx4; stores non-temporal full lines. */
template <bool SORTED>
__global__ __launch_bounds__(256) void k_sample(const float* __restrict__ qp,
                                                const float* __restrict__ px,
                                                const float* __restrict__ py,
                                                const float* __restrict__ pz,
                                                const float* __restrict__ mi,
                                                const int* __restrict__ idp,
                                                const int* __restrict__ perm,
                                                float* __restrict__ out) {
    const int tid  = threadIdx.x;
    const int wv   = tid >> 6;
    const int lane = tid & 63;
    const int pt   = lane >> 4;
    const int jg   = (lane >> 2) & 3;
    const int cq   = lane & 3;
    const int i    = blockIdx.x * PPB + wv * PPW + pt;   /* < NPTS (6250*16) */
    const int p    = SORTED ? perm[i] : i;

    const int id = *idp;
    const size_t sid = (size_t)id * ID_STRIDE;

    const float m0 = mi[0], m1 = mi[1], m2 = mi[2];
    const float i0 = mi[3], i1 = mi[4], i2 = mi[5];

    const float cx = (qp[p * 3 + 0] - m0) * i0;
    const float cy = (qp[p * 3 + 1] - m1) * i1;
    const float cz = (qp[p * 3 + 2] - m2) * i2;

    /* plane 0 (feat_x): gx=cy (W), gy=cx (H)
       plane 1 (feat_y): gx=cz,     gy=cy
       plane 2 (feat_z): gx=cx,     gy=cz  */
    const float gxs[3] = {cy, cz, cx};
    const float gys[3] = {cx, cy, cz};
    const f32x4* base4[3] = {(const f32x4*)(px + sid),
                             (const f32x4*)(py + sid),
                             (const f32x4*)(pz + sid)};

    float w00[3], w01[3], w10[3], w11[3];
    int   v00[3], v01[3], v10[3], v11[3];
#pragma unroll
    for (int pn = 0; pn < 3; ++pn) {
        float fx = fminf(fmaxf((gxs[pn] + 1.0f) * (0.5f * (LL - 1)), 0.0f), (float)(LL - 1));
        float fy = fminf(fmaxf((gys[pn] + 1.0f) * (0.5f * (LL - 1)), 0.0f), (float)(LL - 1));
        int x0 = (int)fx, y0 = (int)fy;
        float wx = fx - (float)x0, wy = fy - (float)y0;
        int x1 = min(x0 + 1, LL - 1), y1 = min(y0 + 1, LL - 1);
        w00[pn] = (1.f - wx) * (1.f - wy);
        w01[pn] = wx * (1.f - wy);
        w10[pn] = (1.f - wx) * wy;
        w11[pn] = wx * wy;
        const int jb = jg * J4 + cq;
        v00[pn] = jb + (y0 * LL + x0) * 4;
        v01[pn] = jb + (y0 * LL + x1) * 4;
        v10[pn] = jb + (y1 * LL + x0) * 4;
        v11[pn] = jb + (y1 * LL + x1) * 4;
    }

    /* out row in f32x4 units: p*288 + jt*48 + jg*12 + pn*4 + cq */
    f32x4* outq = (f32x4*)out + (size_t)p * (NJ * 3 * CC / 4) + jg * 12 + cq;

#pragma unroll
    for (int pn = 0; pn < 3; ++pn) {
        const f32x4* bp = base4[pn];
        const float a00 = w00[pn], a01 = w01[pn], a10 = w10[pn], a11 = w11[pn];
        const int u00 = v00[pn], u01 = v01[pn], u10 = v10[pn], u11 = v11[pn];
#pragma unroll
        for (int jt = 0; jt < 6; ++jt) {
            const f32x4* bj = bp + (size_t)jt * 4 * J4;
            const f32x4 g00 = bj[u00];
            const f32x4 g01 = bj[u01];
            const f32x4 g10 = bj[u10];
            const f32x4 g11 = bj[u11];
            f32x4 r = a00 * g00 + a01 * g01 + a10 * g10 + a11 * g11;
            __builtin_nontemporal_store(r, &outq[jt * 48 + pn * 4]);
        }
    }
}

extern "C" void kernel_launch(void* const* d_in, const int* in_sizes, int n_in,
                              void* d_out, int out_size, void* d_ws, size_t ws_size,
                              hipStream_t stream) {
    const int*   idp   = (const int*)d_in[0];
    const float* qp    = (const float*)d_in[1];
    const float* scale = (const float*)d_in[2];
    const float* px    = (const float*)d_in[3];
    const float* py    = (const float*)d_in[4];
    const float* pz    = (const float*)d_in[5];
    float* out = (float*)d_out;
    float* ws  = (float*)d_ws;
    int*   wsi = (int*)d_ws;

    k_partial<<<RB, 256, 0, stream>>>(qp, ws + WS_PART, wsi + WS_HIST);
    k_final<<<1, 256, 0, stream>>>(ws + WS_PART, scale, ws + WS_MI);

    if (ws_size >= WS_NEEDED) {
        k_keys<<<(NPTS + 255) / 256, 256, 0, stream>>>(qp, ws + WS_MI,
                                                       wsi + WS_KEYS, wsi + WS_HIST);
        k_scan<<<1, 256, 0, stream>>>(wsi + WS_HIST, wsi + WS_OFFS);
        k_scatter<<<(NPTS + 255) / 256, 256, 0, stream>>>(wsi + WS_KEYS,
                                                          wsi + WS_OFFS, wsi + WS_PERM);
        k_sample<true><<<NPTS / PPB, 256, 0, stream>>>(qp, px, py, pz, ws + WS_MI,
                                                       idp, wsi + WS_PERM, out);
    } else {
        k_sample<false><<<NPTS / PPB, 256, 0, stream>>>(qp, px, py, pz, ws + WS_MI,
                                                        idp, (const int*)nullptr, out);
    }
}

// Round 7
// 139.594 us; speedup vs baseline: 1.8626x; 1.8626x over previous
//
#include <hip/hip_runtime.h>
#include <hip/hip_fp16.h>

#define NPTS 100000
#define NJ 24
#define PDIM 64
#define LL 32
#define CC 16
#define JOINT_STRIDE (PDIM*LL*LL*CC)   /* 1<<20 floats = 4 MB per joint */
#define J4 (JOINT_STRIDE/4)            /* float4 stride per joint */
#define ID_STRIDE (LL*LL*CC)           /* 16384 floats = 64 KB slice */
#define SLICE_F 16384                  /* floats per (plane,joint) slice */
#define RB 100                         /* reduce blocks */
#define PPW 4                          /* points per wave */
#define PPB 16                         /* points per block (4 waves) */

/* ws layout: floats [0,300) partials, [384,390) mi; fp16 grid at float idx 1024 */
#define WS_MI 384
#define WS_GRID_F 1024
#define GRID_HALFS (3*NJ*SLICE_F)      /* 1,179,648 halfs = 2.25 MB */
#define WS_NEEDED ((size_t)WS_GRID_F*4 + (size_t)GRID_HALFS*2)

typedef float f32x4 __attribute__((ext_vector_type(4)));

__global__ __launch_bounds__(256) void k_partial(const float* __restrict__ qp,
                                                 float* __restrict__ partial) {
    __shared__ float sm[3][256];
    int tid = threadIdx.x;
    float s0 = 0.f, s1 = 0.f, s2 = 0.f;
    for (int n = blockIdx.x * 256 + tid; n < NPTS; n += RB * 256) {
        s0 += qp[n * 3 + 0];
        s1 += qp[n * 3 + 1];
        s2 += qp[n * 3 + 2];
    }
    sm[0][tid] = s0; sm[1][tid] = s1; sm[2][tid] = s2;
    __syncthreads();
    for (int s = 128; s > 0; s >>= 1) {
        if (tid < s) {
            sm[0][tid] += sm[0][tid + s];
            sm[1][tid] += sm[1][tid + s];
            sm[2][tid] += sm[2][tid + s];
        }
        __syncthreads();
    }
    if (tid == 0) {
        partial[blockIdx.x * 3 + 0] = sm[0][0];
        partial[blockIdx.x * 3 + 1] = sm[1][0];
        partial[blockIdx.x * 3 + 2] = sm[2][0];
    }
}

__global__ __launch_bounds__(256) void k_final(const float* __restrict__ partial,
                                               const float* __restrict__ scale,
                                               float* __restrict__ mi) {
    __shared__ float sm[3][256];
    int tid = threadIdx.x;
    float s0 = 0.f, s1 = 0.f, s2 = 0.f;
    if (tid < RB) {
        s0 = partial[tid * 3 + 0];
        s1 = partial[tid * 3 + 1];
        s2 = partial[tid * 3 + 2];
    }
    sm[0][tid] = s0; sm[1][tid] = s1; sm[2][tid] = s2;
    __syncthreads();
    for (int s = 128; s > 0; s >>= 1) {
        if (tid < s) {
            sm[0][tid] += sm[0][tid + s];
            sm[1][tid] += sm[1][tid + s];
            sm[2][tid] += sm[2][tid + s];
        }
        __syncthreads();
    }
    if (tid == 0) {
        const float invn = 1.0f / (float)NPTS;
        mi[0] = sm[0][0] * invn;
        mi[1] = sm[1][0] * invn;
        mi[2] = sm[2][0] * invn;
        mi[3] = 1.0f / (scale[0] * 0.5f);
        mi[4] = 1.0f / (scale[1] * 0.5f);
        mi[5] = 1.0f / (scale[2] * 0.5f);
    }
}

/* Convert the id-slice of all 3 planes x 24 joints to fp16 in ws.
   dst layout: [pn][j][y][x][ch] contiguous halfs. 16 blocks per slice. */
__global__ __launch_bounds__(256) void k_convert(const float* __restrict__ px,
                                                 const float* __restrict__ py,
                                                 const float* __restrict__ pz,
                                                 const int* __restrict__ idp,
                                                 __half* __restrict__ dst) {
    const int b   = blockIdx.x;
    const int s   = b >> 4;          /* slice 0..71 */
    const int pn  = s / NJ;
    const int j   = s - pn * NJ;
    const int off = (b & 15) * 1024 + threadIdx.x * 4;
    const float* src = (pn == 0 ? px : pn == 1 ? py : pz)
                       + (size_t)(*idp) * ID_STRIDE + (size_t)j * JOINT_STRIDE + off;
    f32x4 v = *(const f32x4*)src;
    __half2 h0 = __float22half2_rn(make_float2(v.x, v.y));
    __half2 h1 = __float22half2_rn(make_float2(v.z, v.w));
    uint2 o;
    o.x = __builtin_bit_cast(unsigned int, h0);
    o.y = __builtin_bit_cast(unsigned int, h1);
    *(uint2*)(dst + (size_t)s * SLICE_F + off) = o;
}

/* fp16-grid sampler. wave = 4 points; lane = (pt, jg, cq).
   Per corner load: uint2 = 4 fp16 channels; 16 lanes/pt cover 4 joints x 32B
   = 128B contiguous (2 lines). 144 line-touches per point (vs 288 f32). */
__global__ __launch_bounds__(256) void k_sample_h(const float* __restrict__ qp,
                                                  const __half* __restrict__ gh,
                                                  const float* __restrict__ mi,
                                                  float* __restrict__ out) {
    const int tid  = threadIdx.x;
    const int wv   = tid >> 6;
    const int lane = tid & 63;
    const int pt   = lane >> 4;
    const int jg   = (lane >> 2) & 3;
    const int cq   = lane & 3;
    const int p    = blockIdx.x * PPB + wv * PPW + pt;   /* < NPTS (6250*16) */

    const float m0 = mi[0], m1 = mi[1], m2 = mi[2];
    const float i0 = mi[3], i1 = mi[4], i2 = mi[5];

    const float cx = (qp[p * 3 + 0] - m0) * i0;
    const float cy = (qp[p * 3 + 1] - m1) * i1;
    const float cz = (qp[p * 3 + 2] - m2) * i2;

    /* plane 0 (feat_x): gx=cy (W), gy=cx (H)
       plane 1 (feat_y): gx=cz,     gy=cy
       plane 2 (feat_z): gx=cx,     gy=cz  */
    const float gxs[3] = {cy, cz, cx};
    const float gys[3] = {cx, cy, cz};

    float w00[3], w01[3], w10[3], w11[3];
    int   v00[3], v01[3], v10[3], v11[3];   /* per-lane half offsets: jg joint + corner + cq */
#pragma unroll
    for (int pn = 0; pn < 3; ++pn) {
        float fx = fminf(fmaxf((gxs[pn] + 1.0f) * (0.5f * (LL - 1)), 0.0f), (float)(LL - 1));
        float fy = fminf(fmaxf((gys[pn] + 1.0f) * (0.5f * (LL - 1)), 0.0f), (float)(LL - 1));
        int x0 = (int)fx, y0 = (int)fy;
        float wx = fx - (float)x0, wy = fy - (float)y0;
        int x1 = min(x0 + 1, LL - 1), y1 = min(y0 + 1, LL - 1);
        w00[pn] = (1.f - wx) * (1.f - wy);
        w01[pn] = wx * (1.f - wy);
        w10[pn] = (1.f - wx) * wy;
        w11[pn] = wx * wy;
        const int jb = jg * SLICE_F + cq * 4;
        v00[pn] = jb + (y0 * LL + x0) * CC;
        v01[pn] = jb + (y0 * LL + x1) * CC;
        v10[pn] = jb + (y1 * LL + x0) * CC;
        v11[pn] = jb + (y1 * LL + x1) * CC;
    }

    /* out row in f32x4 units: p*288 + jt*48 + jg*12 + pn*4 + cq */
    f32x4* outq = (f32x4*)out + (size_t)p * (NJ * 3 * CC / 4) + jg * 12 + cq;

#pragma unroll
    for (int pn = 0; pn < 3; ++pn) {
        const __half* bp = gh + (size_t)pn * (NJ * SLICE_F);
        const float a00 = w00[pn], a01 = w01[pn], a10 = w10[pn], a11 = w11[pn];
        const int u00 = v00[pn], u01 = v01[pn], u10 = v10[pn], u11 = v11[pn];
#pragma unroll
        for (int jt = 0; jt < 6; ++jt) {
            const __half* bj = bp + (size_t)jt * 4 * SLICE_F;
            const uint2 q00 = *(const uint2*)(bj + u00);
            const uint2 q01 = *(const uint2*)(bj + u01);
            const uint2 q10 = *(const uint2*)(bj + u10);
            const uint2 q11 = *(const uint2*)(bj + u11);
            float2 f00a = __half22float2(__builtin_bit_cast(__half2, q00.x));
            float2 f00b = __half22float2(__builtin_bit_cast(__half2, q00.y));
            float2 f01a = __half22float2(__builtin_bit_cast(__half2, q01.x));
            float2 f01b = __half22float2(__builtin_bit_cast(__half2, q01.y));
            float2 f10a = __half22float2(__builtin_bit_cast(__half2, q10.x));
            float2 f10b = __half22float2(__builtin_bit_cast(__half2, q10.y));
            float2 f11a = __half22float2(__builtin_bit_cast(__half2, q11.x));
            float2 f11b = __half22float2(__builtin_bit_cast(__half2, q11.y));
            f32x4 r;
            r.x = a00 * f00a.x + a01 * f01a.x + a10 * f10a.x + a11 * f11a.x;
            r.y = a00 * f00a.y + a01 * f01a.y + a10 * f10a.y + a11 * f11a.y;
            r.z = a00 * f00b.x + a01 * f01b.x + a10 * f10b.x + a11 * f11b.x;
            r.w = a00 * f00b.y + a01 * f01b.y + a10 * f10b.y + a11 * f11b.y;
            __builtin_nontemporal_store(r, &outq[jt * 48 + pn * 4]);
        }
    }
}

/* f32 fallback sampler (R4) if ws is too small for the fp16 grid. */
__global__ __launch_bounds__(256) void k_sample_f(const float* __restrict__ qp,
                                                  const float* __restrict__ px,
                                                  const float* __restrict__ py,
                                                  const float* __restrict__ pz,
                                                  const float* __restrict__ mi,
                                                  const int* __restrict__ idp,
                                                  float* __restrict__ out) {
    const int tid  = threadIdx.x;
    const int wv   = tid >> 6;
    const int lane = tid & 63;
    const int pt   = lane >> 4;
    const int jg   = (lane >> 2) & 3;
    const int cq   = lane & 3;
    const int p    = blockIdx.x * PPB + wv * PPW + pt;

    const int id = *idp;
    const size_t sid = (size_t)id * ID_STRIDE;

    const float m0 = mi[0], m1 = mi[1], m2 = mi[2];
    const float i0 = mi[3], i1 = mi[4], i2 = mi[5];

    const float cx = (qp[p * 3 + 0] - m0) * i0;
    const float cy = (qp[p * 3 + 1] - m1) * i1;
    const float cz = (qp[p * 3 + 2] - m2) * i2;

    const float gxs[3] = {cy, cz, cx};
    const float gys[3] = {cx, cy, cz};
    const f32x4* base4[3] = {(const f32x4*)(px + sid),
                             (const f32x4*)(py + sid),
                             (const f32x4*)(pz + sid)};

    float w00[3], w01[3], w10[3], w11[3];
    int   v00[3], v01[3], v10[3], v11[3];
#pragma unroll
    for (int pn = 0; pn < 3; ++pn) {
        float fx = fminf(fmaxf((gxs[pn] + 1.0f) * (0.5f * (LL - 1)), 0.0f), (float)(LL - 1));
        float fy = fminf(fmaxf((gys[pn] + 1.0f) * (0.5f * (LL - 1)), 0.0f), (float)(LL - 1));
        int x0 = (int)fx, y0 = (int)fy;
        float wx = fx - (float)x0, wy = fy - (float)y0;
        int x1 = min(x0 + 1, LL - 1), y1 = min(y0 + 1, LL - 1);
        w00[pn] = (1.f - wx) * (1.f - wy);
        w01[pn] = wx * (1.f - wy);
        w10[pn] = (1.f - wx) * wy;
        w11[pn] = wx * wy;
        const int jb = jg * J4 + cq;
        v00[pn] = jb + (y0 * LL + x0) * 4;
        v01[pn] = jb + (y0 * LL + x1) * 4;
        v10[pn] = jb + (y1 * LL + x0) * 4;
        v11[pn] = jb + (y1 * LL + x1) * 4;
    }

    f32x4* outq = (f32x4*)out + (size_t)p * (NJ * 3 * CC / 4) + jg * 12 + cq;

#pragma unroll
    for (int pn = 0; pn < 3; ++pn) {
        const f32x4* bp = base4[pn];
        const float a00 = w00[pn], a01 = w01[pn], a10 = w10[pn], a11 = w11[pn];
        const int u00 = v00[pn], u01 = v01[pn], u10 = v10[pn], u11 = v11[pn];
#pragma unroll
        for (int jt = 0; jt < 6; ++jt) {
            const f32x4* bj = bp + (size_t)jt * 4 * J4;
            const f32x4 g00 = bj[u00];
            const f32x4 g01 = bj[u01];
            const f32x4 g10 = bj[u10];
            const f32x4 g11 = bj[u11];
            f32x4 r = a00 * g00 + a01 * g01 + a10 * g10 + a11 * g11;
            __builtin_nontemporal_store(r, &outq[jt * 48 + pn * 4]);
        }
    }
}

extern "C" void kernel_launch(void* const* d_in, const int* in_sizes, int n_in,
                              void* d_out, int out_size, void* d_ws, size_t ws_size,
                              hipStream_t stream) {
    const int*   idp   = (const int*)d_in[0];
    const float* qp    = (const float*)d_in[1];
    const float* scale = (const float*)d_in[2];
    const float* px    = (const float*)d_in[3];
    const float* py    = (const float*)d_in[4];
    const float* pz    = (const float*)d_in[5];
    float* out = (float*)d_out;
    float* ws  = (float*)d_ws;

    k_partial<<<RB, 256, 0, stream>>>(qp, ws);
    k_final<<<1, 256, 0, stream>>>(ws, scale, ws + WS_MI);

    if (ws_size >= WS_NEEDED) {
        __half* gh = (__half*)(ws + WS_GRID_F);
        k_convert<<<72 * 16, 256, 0, stream>>>(px, py, pz, idp, gh);
        k_sample_h<<<NPTS / PPB, 256, 0, stream>>>(qp, gh, ws + WS_MI, out);
    } else {
        k_sample_f<<<NPTS / PPB, 256, 0, stream>>>(qp, px, py, pz, ws + WS_MI, idp, out);
    }
}